// Round 3
// baseline (512.889 us; speedup 1.0000x reference)
//
#include <hip/hip_runtime.h>

// LIF spiking-neuron scan: spikes[b,c,h,w,t], final_v, final_reset.
// Memory-bound streaming kernel. Strategy: block = 256 consecutive pixels ->
// contiguous 51.2KB global span; stage via LDS to convert the stride-200B
// per-pixel T-series into fully coalesced float4 global traffic.
// Streams are touch-once -> nontemporal load/store (gfx950 'nt' flag).
// [R2: held byte-stable — 3x GPU acquisition timeouts, no counters to act on]

#define T_STEPS 50
#define PPB 256              // pixels per block (== blockDim.x)
#define ROW 51               // LDS row pad: 51 % 32 = 19, coprime with 32 -> conflict-free column reads
#define CHW 49152            // 3*128*128
#define NPIX 1572864         // 32 * CHW
#define SPIKES_ELEMS 78643200LL  // NPIX * T
#define F4_PER_BLOCK 3200    // PPB*T_STEPS/4

typedef float f32x4 __attribute__((ext_vector_type(4)));

__global__ __launch_bounds__(PPB) void snn_lif_kernel(
    const float* __restrict__ in,      // [B,C,H,W,T]
    const float* __restrict__ weight,  // [C,H,W]
    const float* __restrict__ gain,    // [C,H,W]
    float* __restrict__ out)           // spikes | final_v | final_reset
{
    __shared__ float lds[PPB * ROW];   // 52,224 B -> 3 blocks/CU
    const int tid = threadIdx.x;
    const int blk = blockIdx.x;
    const long long base_elem = (long long)blk * (PPB * T_STEPS);

    // ---- stage in: coalesced nontemporal float4 loads, transpose-scatter into LDS ----
    const f32x4* in4 = (const f32x4*)(in + base_elem);
    #pragma unroll
    for (int k = 0; k < 13; ++k) {
        int idx4 = k * PPB + tid;
        if (idx4 < F4_PER_BLOCK) {
            f32x4 v4 = __builtin_nontemporal_load(&in4[idx4]);
            int f = idx4 * 4;
            #pragma unroll
            for (int e = 0; e < 4; ++e) {
                int fe = f + e;
                int p  = fe / T_STEPS;          // magic-mul, cheap
                int t  = fe - p * T_STEPS;
                lds[p * ROW + t] = v4[e];
            }
        }
    }
    __syncthreads();

    // ---- per-pixel recurrence over T (in-place spike overwrite in LDS) ----
    const int gp  = blk * PPB + tid;   // global pixel in [0, NPIX)
    const int chw = gp % CHW;
    const float w = weight[chw];
    const float g = gain[chw];
    // correctly-rounded f32 exp(-1/4); 1-decay folded at compile time.
    const float decay = 0.77880078307140486825f;
    const float omd   = 1.0f - decay;

    float v = 0.0f, r = 0.0f;
    float* myrow = &lds[tid * ROW];
    #pragma unroll
    for (int t = 0; t < T_STEPS; ++t) {
        float x  = myrow[t];
        // match reference rounding exactly: no fma contraction.
        float wp   = __fmul_rn(w, x);
        float term = __fmul_rn(__fmul_rn(g, wp), omd);
        v = __fadd_rn(__fmul_rn(v, decay), term);
        float spike = (v > 1.0f) ? 1.0f : 0.0f;
        r = __fadd_rn(__fmul_rn(r, decay), spike);
        myrow[t] = spike;
    }
    __syncthreads();

    // ---- write back spikes: gather from LDS, coalesced nontemporal float4 stores ----
    f32x4* out4 = (f32x4*)(out + base_elem);
    #pragma unroll
    for (int k = 0; k < 13; ++k) {
        int idx4 = k * PPB + tid;
        if (idx4 < F4_PER_BLOCK) {
            int f = idx4 * 4;
            f32x4 v4;
            #pragma unroll
            for (int e = 0; e < 4; ++e) {
                int fe = f + e;
                int p  = fe / T_STEPS;
                int t  = fe - p * T_STEPS;
                v4[e] = lds[p * ROW + t];
            }
            __builtin_nontemporal_store(v4, &out4[idx4]);
        }
    }

    // ---- final states ----
    out[SPIKES_ELEMS + gp] = v;
    out[SPIKES_ELEMS + NPIX + gp] = r;
}

extern "C" void kernel_launch(void* const* d_in, const int* in_sizes, int n_in,
                              void* d_out, int out_size, void* d_ws, size_t ws_size,
                              hipStream_t stream) {
    const float* in     = (const float*)d_in[0];
    const float* weight = (const float*)d_in[1];
    const float* gain   = (const float*)d_in[2];
    // d_in[3] (bias) is unused by the reference's v_calculate_method==0 path.
    float* out = (float*)d_out;

    dim3 grid(NPIX / PPB);   // 6144 blocks
    dim3 block(PPB);
    hipLaunchKernelGGL(snn_lif_kernel, grid, block, 0, stream, in, weight, gain, out);
}

// Round 4
// 511.550 us; speedup vs baseline: 1.0026x; 1.0026x over previous
//
#include <hip/hip_runtime.h>

// LIF spiking-neuron scan: spikes[b,c,h,w,t], final_v, final_reset.
// Memory-bound streaming kernel. Block = 256 consecutive pixels = contiguous
// 51.2KB global span, mirrored LINEARLY into LDS (no transpose scatter).
// R3 restructure: all LDS ops vectorized —
//   stage: 13x ds_write_b128 (linear, conflict-free)
//   compute: 25x ds_read_b64 + 25x ds_write_b64 at dword-stride 50
//            (50*dLane mod 32 covers all banks per 16-lane group -> conflict-free)
//   writeback: 13x ds_read_b128 (linear)
// LDS ops/wave 204 -> 76; scatter div/mod VALU eliminated.

#define T_STEPS 50
#define PPB 256              // pixels per block (== blockDim.x)
#define CHW 49152            // 3*128*128
#define NPIX 1572864         // 32 * CHW
#define SPIKES_ELEMS 78643200LL  // NPIX * T
#define F4_PER_BLOCK 3200    // PPB*T_STEPS/4

typedef float f32x4 __attribute__((ext_vector_type(4)));
typedef float f32x2 __attribute__((ext_vector_type(2)));

__global__ __launch_bounds__(PPB) void snn_lif_kernel(
    const float* __restrict__ in,      // [B,C,H,W,T]
    const float* __restrict__ weight,  // [C,H,W]
    const float* __restrict__ gain,    // [C,H,W]
    float* __restrict__ out)           // spikes | final_v | final_reset
{
    __shared__ f32x4 lds4[F4_PER_BLOCK];   // 53,248 B -> 3 blocks/CU (159,744 <= 163,840)
    const int tid = threadIdx.x;
    const int blk = blockIdx.x;
    const long long base_elem = (long long)blk * (PPB * T_STEPS);

    // ---- stage in: coalesced nontemporal float4 loads -> linear LDS image ----
    const f32x4* in4 = (const f32x4*)(in + base_elem);
    #pragma unroll
    for (int k = 0; k < 13; ++k) {
        int idx4 = k * PPB + tid;
        if (idx4 < F4_PER_BLOCK) {
            lds4[idx4] = __builtin_nontemporal_load(&in4[idx4]);
        }
    }
    __syncthreads();

    // ---- per-pixel recurrence over T, 2 steps per ds_read_b64/ds_write_b64 ----
    const int gp  = blk * PPB + tid;   // global pixel in [0, NPIX)
    const int chw = gp % CHW;
    const float w = weight[chw];
    const float g = gain[chw];
    // correctly-rounded f32 exp(-1/4); 1-decay folded at compile time.
    const float decay = 0.77880078307140486825f;
    const float omd   = 1.0f - decay;

    float v = 0.0f, r = 0.0f;
    // thread's pixel row: 200 B at byte offset tid*200 (8B-aligned)
    f32x2* row = (f32x2*)((char*)lds4 + tid * (T_STEPS * 4));
    #pragma unroll
    for (int j = 0; j < T_STEPS / 2; ++j) {
        f32x2 x2 = row[j];
        f32x2 s2;
        #pragma unroll
        for (int e = 0; e < 2; ++e) {
            // match reference rounding exactly: no fma contraction.
            float wp   = __fmul_rn(w, x2[e]);
            float term = __fmul_rn(__fmul_rn(g, wp), omd);
            v = __fadd_rn(__fmul_rn(v, decay), term);
            float spike = (v > 1.0f) ? 1.0f : 0.0f;
            r = __fadd_rn(__fmul_rn(r, decay), spike);
            s2[e] = spike;
        }
        row[j] = s2;   // in-place overwrite, same thread same address
    }
    __syncthreads();

    // ---- write back spikes: linear LDS reads, coalesced nontemporal stores ----
    f32x4* out4 = (f32x4*)(out + base_elem);
    #pragma unroll
    for (int k = 0; k < 13; ++k) {
        int idx4 = k * PPB + tid;
        if (idx4 < F4_PER_BLOCK) {
            __builtin_nontemporal_store(lds4[idx4], &out4[idx4]);
        }
    }

    // ---- final states ----
    out[SPIKES_ELEMS + gp] = v;
    out[SPIKES_ELEMS + NPIX + gp] = r;
}

extern "C" void kernel_launch(void* const* d_in, const int* in_sizes, int n_in,
                              void* d_out, int out_size, void* d_ws, size_t ws_size,
                              hipStream_t stream) {
    const float* in     = (const float*)d_in[0];
    const float* weight = (const float*)d_in[1];
    const float* gain   = (const float*)d_in[2];
    // d_in[3] (bias) is unused by the reference's v_calculate_method==0 path.
    float* out = (float*)d_out;

    dim3 grid(NPIX / PPB);   // 6144 blocks
    dim3 block(PPB);
    hipLaunchKernelGGL(snn_lif_kernel, grid, block, 0, stream, in, weight, gain, out);
}

// Round 5
// 507.485 us; speedup vs baseline: 1.0106x; 1.0080x over previous
//
#include <hip/hip_runtime.h>

// LIF spiking-neuron scan: spikes[b,c,h,w,t], final_v, final_reset.
// Memory-bound streaming kernel. R5: WAVE-AUTONOMOUS — the pixel-major <->
// coalesced transpose is wave-local (wave w owns pixels [64w,64w+64), a
// private 12.8KB LDS region, and a contiguous 12.8KB global span), so the
// block-wide __syncthreads() convoy (vmcnt(0)-draining barriers synchronizing
// 3 resident blocks/CU in lockstep) is pure overhead. Replaced with
// __threadfence_block() (s_waitcnt lgkmcnt(0), no s_barrier) + wave_barrier.
//   stage: 13x ds_write_b128 (linear), compute: 25x ds_read_b64 + 25x
//   ds_write_b64 at dword-stride 50 (conflict-free), writeback: 13x ds_read_b128.

#define T_STEPS 50
#define PPB 256              // pixels per block (== blockDim.x)
#define CHW 49152            // 3*128*128
#define NPIX 1572864         // 32 * CHW
#define SPIKES_ELEMS 78643200LL  // NPIX * T
#define F4_PER_WAVE 800      // 64 px * 50 T / 4

typedef float f32x4 __attribute__((ext_vector_type(4)));
typedef float f32x2 __attribute__((ext_vector_type(2)));

__global__ __launch_bounds__(PPB) void snn_lif_kernel(
    const float* __restrict__ in,      // [B,C,H,W,T]
    const float* __restrict__ weight,  // [C,H,W]
    const float* __restrict__ gain,    // [C,H,W]
    float* __restrict__ out)           // spikes | final_v | final_reset
{
    __shared__ f32x4 lds4[PPB * T_STEPS / 4];   // 51,200 B -> 3 blocks/CU
    const int tid  = threadIdx.x;
    const int lane = tid & 63;
    const int wid  = tid >> 6;
    const int blk  = blockIdx.x;
    const long long base_elem = (long long)blk * (PPB * T_STEPS);
    const int wbase = wid * F4_PER_WAVE;   // wave's private f4 region

    // ---- stage in: coalesced nontemporal float4 loads -> linear LDS (wave-local) ----
    const f32x4* in4 = (const f32x4*)(in + base_elem);
    #pragma unroll
    for (int k = 0; k < 13; ++k) {
        int i = k * 64 + lane;
        if (i < F4_PER_WAVE) {
            lds4[wbase + i] = __builtin_nontemporal_load(&in4[wbase + i]);
        }
    }
    // wave-local LDS visibility: lgkmcnt(0) drain + compiler fence, NO s_barrier
    __threadfence_block();
    __builtin_amdgcn_wave_barrier();

    // ---- per-pixel recurrence over T, 2 steps per ds_read_b64/ds_write_b64 ----
    const int gp  = blk * PPB + tid;   // global pixel in [0, NPIX)
    const int chw = gp % CHW;
    const float w = weight[chw];
    const float g = gain[chw];
    // correctly-rounded f32 exp(-1/4); 1-decay folded at compile time.
    const float decay = 0.77880078307140486825f;
    const float omd   = 1.0f - decay;

    float v = 0.0f, r = 0.0f;
    // thread's pixel row: 200 B at byte offset tid*200 (8B-aligned), inside wave region
    f32x2* row = (f32x2*)((char*)lds4 + tid * (T_STEPS * 4));
    #pragma unroll
    for (int j = 0; j < T_STEPS / 2; ++j) {
        f32x2 x2 = row[j];
        f32x2 s2;
        #pragma unroll
        for (int e = 0; e < 2; ++e) {
            // match reference rounding exactly: no fma contraction.
            float wp   = __fmul_rn(w, x2[e]);
            float term = __fmul_rn(__fmul_rn(g, wp), omd);
            v = __fadd_rn(__fmul_rn(v, decay), term);
            float spike = (v > 1.0f) ? 1.0f : 0.0f;
            r = __fadd_rn(__fmul_rn(r, decay), spike);
            s2[e] = spike;
        }
        row[j] = s2;   // in-place overwrite, same thread same address
    }
    __threadfence_block();
    __builtin_amdgcn_wave_barrier();

    // ---- write back spikes: linear wave-local LDS reads, coalesced nt stores ----
    f32x4* out4 = (f32x4*)(out + base_elem);
    #pragma unroll
    for (int k = 0; k < 13; ++k) {
        int i = k * 64 + lane;
        if (i < F4_PER_WAVE) {
            __builtin_nontemporal_store(lds4[wbase + i], &out4[wbase + i]);
        }
    }

    // ---- final states ----
    out[SPIKES_ELEMS + gp] = v;
    out[SPIKES_ELEMS + NPIX + gp] = r;
}

extern "C" void kernel_launch(void* const* d_in, const int* in_sizes, int n_in,
                              void* d_out, int out_size, void* d_ws, size_t ws_size,
                              hipStream_t stream) {
    const float* in     = (const float*)d_in[0];
    const float* weight = (const float*)d_in[1];
    const float* gain   = (const float*)d_in[2];
    // d_in[3] (bias) is unused by the reference's v_calculate_method==0 path.
    float* out = (float*)d_out;

    dim3 grid(NPIX / PPB);   // 6144 blocks
    dim3 block(PPB);
    hipLaunchKernelGGL(snn_lif_kernel, grid, block, 0, stream, in, weight, gain, out);
}